// Round 5
// baseline (301.798 us; speedup 1.0000x reference)
//
#include <hip/hip_runtime.h>
#include <stdint.h>

#define S_SCALE 11.313708498984761f
#define EPS 1e-12f

typedef __bf16 bf16x8 __attribute__((ext_vector_type(8)));
typedef float  f32x4  __attribute__((ext_vector_type(4)));

__device__ __forceinline__ f32x4 mfma16(bf16x8 a, bf16x8 b, f32x4 c) {
  return __builtin_amdgcn_mfma_f32_16x16x32_bf16(a, b, c, 0, 0, 0);
}

__device__ __forceinline__ float waveSum(float v) {
#pragma unroll
  for (int m = 32; m > 0; m >>= 1) v += __shfl_xor(v, m, 64);
  return v;
}

// async global->LDS DMA, 16B per lane, LDS dest = uniform base + lane*16
__device__ __forceinline__ void load_lds16(const float* g, float* l) {
  __builtin_amdgcn_global_load_lds(
      (const __attribute__((address_space(1))) uint32_t*)g,
      (__attribute__((address_space(3))) uint32_t*)l, 16, 0, 0);
}

// ---- ws layout (byte offsets) ----
// W bf16 [128][3072]       : [0, 786432)
// bias2 f32 [128]          : [786432, 786944)
// fn bf16 [8192][128]      : [786944, 2884096)
// Zp f32 [2][4][32][256]   : [2884096, 3146240)
#define OFF_W    0
#define OFF_BIAS 786432
#define OFF_FN   786944
#define OFF_ZP   2884096

// ---------------- k_prep: W = fc1_w @ conv_w (blocks 0..191, o-half x k32)
//                  bias2[o] = fc1_w[o,:].conv_b + fc1_b[o] (blocks 192..319)
__global__ __launch_bounds__(256) void k_prep(const float* __restrict__ conv_w,
                                              const float* __restrict__ fc1_w,
                                              const float* __restrict__ conv_b,
                                              const float* __restrict__ fc1_b,
                                              __bf16* __restrict__ W,
                                              float* __restrict__ bias2,
                                              float* __restrict__ loss) {
  __shared__ float cw_s[64][36];    // [c][k], padded
  __shared__ float fc1_s[64][65];   // [o][c], padded
  __shared__ float red[4];
  const int t = threadIdx.x;
  if (blockIdx.x >= 192) {
    // ---- bias path ----
    const int o = blockIdx.x - 192;
    if (o == 0 && t == 0) loss[0] = 0.f;
    float p = fc1_w[o * 512 + t] * conv_b[t] +
              fc1_w[o * 512 + 256 + t] * conv_b[256 + t];
    p = waveSum(p);
    if ((t & 63) == 0) red[t >> 6] = p;
    __syncthreads();
    if (t == 0) bias2[o] = red[0] + red[1] + red[2] + red[3] + fc1_b[o];
    return;
  }
  // ---- fused-weight path: block = (o-half, k-chunk of 32) ----
  const int oh = blockIdx.x & 1;
  const int kt = blockIdx.x >> 1;  // 0..95
  const int k0 = kt * 32, o0 = oh * 64;
  const int og = t >> 3, kg = t & 7;  // thread tile: 2 o x 4 k
  float acc[2][4] = {};
  for (int cs = 0; cs < 8; ++cs) {
    const int cc = cs * 64;
    __syncthreads();
#pragma unroll
    for (int i = 0; i < 8; ++i) {
      int idx = t + 256 * i;
      int cr = idx >> 5, kk = idx & 31;
      cw_s[cr][kk] = conv_w[(cc + cr) * 3072 + k0 + kk];
    }
#pragma unroll
    for (int i = 0; i < 4; ++i) {
      int idx = t + 256 * i;
      int o = idx >> 4, c4 = (idx & 15) * 4;
      float4 v = *(const float4*)&fc1_w[(o0 + o) * 512 + cc + c4];
      fc1_s[o][c4 + 0] = v.x; fc1_s[o][c4 + 1] = v.y;
      fc1_s[o][c4 + 2] = v.z; fc1_s[o][c4 + 3] = v.w;
    }
    __syncthreads();
    for (int ci = 0; ci < 64; ++ci) {
      float4 cw = *(const float4*)&cw_s[ci][kg * 4];
#pragma unroll
      for (int j = 0; j < 2; ++j) {
        float fv = fc1_s[og * 2 + j][ci];
        acc[j][0] = fmaf(fv, cw.x, acc[j][0]);
        acc[j][1] = fmaf(fv, cw.y, acc[j][1]);
        acc[j][2] = fmaf(fv, cw.z, acc[j][2]);
        acc[j][3] = fmaf(fv, cw.w, acc[j][3]);
      }
    }
  }
#pragma unroll
  for (int j = 0; j < 2; ++j)
#pragma unroll
    for (int q = 0; q < 4; ++q)
      W[(o0 + og * 2 + j) * 3072 + k0 + kg * 4 + q] = (__bf16)acc[j][q];
}

// ---------------- k_gemm1f: M=64 block, full K, fused epilogue -------------
// 128 blocks x 512 thr (8 waves: 4 M-groups x 2 N-groups; wave = 16 rows x
// 64 cols). 24 bodies of BK=128, double-buffered LDS (2 x 32 KB). Per body:
// issue DMA(t+1) + B-regs(t+1), compute(t), one __syncthreads.
// Rationale: W-ingress = (8192/M_block)*786KB; M=16 cost 402 MB of L2/LLC
// re-reads (the measured ~7.3 TB/s ingress ceiling). M=64 cuts it to 100 MB.
// A LDS XOR-swizzled in 16B chunks: phys_chunk = log_chunk ^ (row&15).
__global__ __launch_bounds__(512, 2) void k_gemm1f(const float* __restrict__ x,
                                                   const __bf16* __restrict__ W,
                                                   const float* __restrict__ bias2,
                                                   float* __restrict__ f,
                                                   __bf16* __restrict__ fn) {
  __shared__ __align__(16) float A_lds[2][64 * 128];  // 2 x 32 KB
  __shared__ float rsum[64][2];
  __shared__ float rinv[64];
  const int t = threadIdx.x;  // 0..511
  const int wave = t >> 6, lane = t & 63;
  const int wm = wave >> 1, wn = wave & 1;  // 4 M-groups x 2 N-groups
  const int l15 = lane & 15, quad = (lane >> 4) & 3;
  const int m0 = blockIdx.x * 64;

  // DMA mapping: inst j (0..3) of wave covers LDS floats [(wave*4+j)*256..+255]
  // = rows r=(wave*4+j)*2+(lane>>5), phys chunk cp=lane&31, logical chunk
  // cl = cp ^ (r&15), global col = cl*4 (XOR touches only low 4 of 5 bits).
  int drows[4], dcols[4];
#pragma unroll
  for (int j = 0; j < 4; ++j) {
    int r = (wave * 4 + j) * 2 + (lane >> 5);
    int cl = (lane & 31) ^ (r & 15);
    drows[j] = r;
    dcols[j] = cl * 4;
  }
  const __bf16* bp = W + (wn * 64 + l15) * 3072 + quad * 8;

  f32x4 acc[4] = {{0.f, 0.f, 0.f, 0.f}, {0.f, 0.f, 0.f, 0.f},
                  {0.f, 0.f, 0.f, 0.f}, {0.f, 0.f, 0.f, 0.f}};
  uint4 bX[4][4], bY[4][4];  // [ks][ni], double-buffered

  auto burstD = [&](int S, int half) {  // x DMA for body S -> A_lds[half]
#pragma unroll
    for (int j = 0; j < 4; ++j)
      load_lds16(x + (m0 + drows[j]) * 3072 + S * 128 + dcols[j],
                 &A_lds[half][(wave * 4 + j) * 256]);
  };
  auto loadB = [&](int S, uint4(&d)[4][4]) {  // B regs for body S
#pragma unroll
    for (int ks = 0; ks < 4; ++ks)
#pragma unroll
      for (int ni = 0; ni < 4; ++ni)
        d[ks][ni] = *(const uint4*)(bp + ni * 16 * 3072 + S * 128 + ks * 32);
  };
  auto computeB = [&](int half, const uint4(&d)[4][4]) {
    const float* Abuf = &A_lds[half][0];
    const int arow = wm * 16 + l15;        // arow & 15 == l15
    const int rb = arow * 128;
#pragma unroll
    for (int ks = 0; ks < 4; ++ks) {
      float4 lo = *(const float4*)&Abuf[rb + (((ks * 8 + quad * 2 + 0) ^ l15) << 2)];
      float4 hi = *(const float4*)&Abuf[rb + (((ks * 8 + quad * 2 + 1) ^ l15) << 2)];
      union { __bf16 h[8]; bf16x8 v; } pk;
      pk.h[0] = (__bf16)lo.x; pk.h[1] = (__bf16)lo.y;
      pk.h[2] = (__bf16)lo.z; pk.h[3] = (__bf16)lo.w;
      pk.h[4] = (__bf16)hi.x; pk.h[5] = (__bf16)hi.y;
      pk.h[6] = (__bf16)hi.z; pk.h[7] = (__bf16)hi.w;
      bf16x8 af = pk.v;
#pragma unroll
      for (int ni = 0; ni < 4; ++ni)
        acc[ni] = mfma16(af, *(const bf16x8*)&d[ks][ni], acc[ni]);
    }
  };

  // prologue: body 0 staged
  burstD(0, 0);
  loadB(0, bX);
  __syncthreads();

  for (int s2 = 0; s2 < 12; ++s2) {
    const int S0 = s2 * 2;
    // body S0: prefetch S0+1 -> half1/bY, compute half0/bX
    burstD(S0 + 1, 1);
    loadB(S0 + 1, bY);
    __builtin_amdgcn_sched_barrier(0);  // pin prefetch issue before compute
    computeB(0, bX);
    __syncthreads();
    // body S0+1: prefetch S0+2 -> half0/bX (unless last), compute half1/bY
    if (s2 < 11) {
      burstD(S0 + 2, 0);
      loadB(S0 + 2, bX);
    }
    __builtin_amdgcn_sched_barrier(0);
    computeB(1, bY);
    __syncthreads();
  }

  // ---- fused finalize: bias, row L2-norm over 128 cols, write f + fn ----
#pragma unroll
  for (int ni = 0; ni < 4; ++ni) {
    const float bv = bias2[wn * 64 + ni * 16 + l15];
#pragma unroll
    for (int r = 0; r < 4; ++r) acc[ni][r] += bv;
  }
#pragma unroll
  for (int r = 0; r < 4; ++r) {
    float s = 0.f;
#pragma unroll
    for (int ni = 0; ni < 4; ++ni) s = fmaf(acc[ni][r], acc[ni][r], s);
    s += __shfl_xor(s, 1, 64);
    s += __shfl_xor(s, 2, 64);
    s += __shfl_xor(s, 4, 64);
    s += __shfl_xor(s, 8, 64);  // sum over l15 (64 cols of this N-group)
    if (l15 == 0) rsum[wm * 16 + quad * 4 + r][wn] = s;
  }
  __syncthreads();
  if (t < 64) rinv[t] = 1.f / fmaxf(sqrtf(rsum[t][0] + rsum[t][1]), EPS);
  __syncthreads();
#pragma unroll
  for (int r = 0; r < 4; ++r) {
    const int row = wm * 16 + quad * 4 + r;
    const float iv = rinv[row];
#pragma unroll
    for (int ni = 0; ni < 4; ++ni) {
      const int g = (m0 + row) * 128 + wn * 64 + ni * 16 + l15;
      f[g] = acc[ni][r];
      fn[g] = (__bf16)(acc[ni][r] * iv);
    }
  }
}

// ---------------- A[b] = fn_b @ fn_b^T  +  fused Z column-partials ---------
// Zp[z][ti][b][m]: partial (over 64 rows of ti) column sums of E*(1-eye)*drop.
__global__ __launch_bounds__(256) void k_gemm2(const __bf16* __restrict__ fn,
                                               const float* __restrict__ d1,
                                               const float* __restrict__ d2,
                                               float* __restrict__ Aout,
                                               float* __restrict__ Zp) {
  __shared__ __align__(16) __bf16 Li[64][136];
  __shared__ __align__(16) __bf16 Lj[64][136];
  __shared__ float zred[2][4][64];
  const int t = threadIdx.x;
  const int b = blockIdx.y;
  const int ti = blockIdx.x >> 2, tj = blockIdx.x & 3;
  const int i0 = ti * 64, j0 = tj * 64;
  const int wave = t >> 6, lane = t & 63;
  const int l15 = lane & 15, quad = lane >> 4;
  const __bf16* fb = fn + b * 32768;
#pragma unroll
  for (int i = 0; i < 4; ++i) {
    int idx = t + 256 * i;
    int r = idx >> 4, c8 = (idx & 15) * 8;
    *(uint4*)&Li[r][c8] = *(const uint4*)&fb[(i0 + r) * 128 + c8];
    *(uint4*)&Lj[r][c8] = *(const uint4*)&fb[(j0 + r) * 128 + c8];
  }
  __syncthreads();
  f32x4 acc[4] = {{0.f, 0.f, 0.f, 0.f}, {0.f, 0.f, 0.f, 0.f},
                  {0.f, 0.f, 0.f, 0.f}, {0.f, 0.f, 0.f, 0.f}};
#pragma unroll
  for (int ks = 0; ks < 4; ++ks) {
    bf16x8 af = *(const bf16x8*)&Li[wave * 16 + l15][ks * 32 + quad * 8];
#pragma unroll
    for (int nt = 0; nt < 4; ++nt) {
      bf16x8 bf = *(const bf16x8*)&Lj[nt * 16 + l15][ks * 32 + quad * 8];
      acc[nt] = mfma16(af, bf, acc[nt]);
    }
  }
  const int base = b * 65536;
  float* Ab = Aout + base;
  float z1c[4] = {0.f, 0.f, 0.f, 0.f}, z2c[4] = {0.f, 0.f, 0.f, 0.f};
#pragma unroll
  for (int nt = 0; nt < 4; ++nt) {
    int gj = j0 + nt * 16 + l15;
#pragma unroll
    for (int r = 0; r < 4; ++r) {
      int gi = i0 + wave * 16 + quad * 4 + r;
      float a = acc[nt][r];
      Ab[gi * 256 + gj] = a;
      float e = __expf(fmaf(S_SCALE, a, -S_SCALE));
      if (gi != gj) {
        int idx = base + gi * 256 + gj;
        z1c[nt] = fmaf(e, d1[idx], z1c[nt]);
        z2c[nt] = fmaf(e, d2[idx], z2c[nt]);
      }
    }
  }
#pragma unroll
  for (int nt = 0; nt < 4; ++nt) {
    z1c[nt] += __shfl_xor(z1c[nt], 16, 64);
    z1c[nt] += __shfl_xor(z1c[nt], 32, 64);
    z2c[nt] += __shfl_xor(z2c[nt], 16, 64);
    z2c[nt] += __shfl_xor(z2c[nt], 32, 64);
  }
  if (quad == 0) {
#pragma unroll
    for (int nt = 0; nt < 4; ++nt) {
      zred[0][wave][nt * 16 + l15] = z1c[nt];
      zred[1][wave][nt * 16 + l15] = z2c[nt];
    }
  }
  __syncthreads();
  if (t < 128) {
    int z = t >> 6, c = t & 63;
    float s = zred[z][0][c] + zred[z][1][c] + zred[z][2][c] + zred[z][3][c];
    Zp[(z * 4 + ti) * 8192 + b * 256 + j0 + c] = s;
  }
}

// ---------------- loss = -1/8192 * sum E^2*d2[i,k]*d1[k,i]/(Z2[k]Z1[i]) ----
__global__ __launch_bounds__(256) void k_loss(const float* __restrict__ Aout,
                                              const float* __restrict__ d1,
                                              const float* __restrict__ d2,
                                              const float* __restrict__ Zp,
                                              float* __restrict__ loss) {
  __shared__ float d1s[64][65];  // d1[k][i] tile, transposed access
  __shared__ float z1s[64], z2s[64];
  __shared__ float red[4];
  const int t = threadIdx.x;
  const int b = blockIdx.y;
  const int ic = blockIdx.x >> 2, kc = blockIdx.x & 3;
  const int i0 = ic * 64, k0 = kc * 64;
  const int base = b * 65536;
  if (t < 64) {
    float s = 0.f;
#pragma unroll
    for (int p = 0; p < 4; ++p) s += Zp[p * 8192 + b * 256 + i0 + t];
    z1s[t] = 1.f / fmaxf(s, EPS);
  } else if (t < 128) {
    float s = 0.f;
#pragma unroll
    for (int p = 0; p < 4; ++p) s += Zp[(4 + p) * 8192 + b * 256 + k0 + t - 64];
    z2s[t - 64] = 1.f / fmaxf(s, EPS);
  }
#pragma unroll
  for (int ii = 0; ii < 16; ++ii) {
    int idx = t + 256 * ii;
    int kr = idx >> 6, ci = idx & 63;
    d1s[kr][ci] = d1[base + (k0 + kr) * 256 + i0 + ci];
  }
  __syncthreads();
  const int kl = t & 63, ig = t >> 6;
  float inv2 = z2s[kl];
  float accv = 0.f;
  for (int ii = 0; ii < 16; ++ii) {
    int il = ig * 16 + ii;
    int idx = base + (i0 + il) * 256 + k0 + kl;
    float a = Aout[idx];
    float e = __expf(fmaf(2.f * S_SCALE, a, -2.f * S_SCALE));
    float v = e * d2[idx] * d1s[kl][il] * z1s[il] * inv2;
    if (i0 + il != k0 + kl) accv += v;
  }
  accv = waveSum(accv);
  if ((t & 63) == 0) red[t >> 6] = accv;
  __syncthreads();
  if (t == 0) {
    float tot = red[0] + red[1] + red[2] + red[3];
    atomicAdd(loss, tot * (-1.f / 8192.f));
  }
}

extern "C" void kernel_launch(void* const* d_in, const int* in_sizes, int n_in,
                              void* d_out, int out_size, void* d_ws,
                              size_t ws_size, hipStream_t stream) {
  const float* x = (const float*)d_in[0];
  const float* conv_w = (const float*)d_in[1];
  const float* conv_b = (const float*)d_in[2];
  const float* fc1_w = (const float*)d_in[3];
  const float* fc1_b = (const float*)d_in[4];
  const float* drop1 = (const float*)d_in[5];
  const float* drop2 = (const float*)d_in[6];
  char* ws = (char*)d_ws;
  __bf16* W = (__bf16*)(ws + OFF_W);
  float* bias2 = (float*)(ws + OFF_BIAS);
  __bf16* fn = (__bf16*)(ws + OFF_FN);
  float* Zp = (float*)(ws + OFF_ZP);
  float* f = (float*)d_out;         // [8192,128]
  float* Aout = f + 1048576;        // [32,256,256]
  float* loss = f + 3145728;        // scalar

  k_prep<<<320, 256, 0, stream>>>(conv_w, fc1_w, conv_b, fc1_b, W, bias2, loss);
  k_gemm1f<<<128, 512, 0, stream>>>(x, W, bias2, f, fn);
  k_gemm2<<<dim3(16, 32), 256, 0, stream>>>(fn, drop1, drop2, Aout, Zp);
  k_loss<<<dim3(16, 32), 256, 0, stream>>>(Aout, drop1, drop2, Zp, loss);
}

// Round 6
// 245.925 us; speedup vs baseline: 1.2272x; 1.2272x over previous
//
#include <hip/hip_runtime.h>
#include <stdint.h>

#define S_SCALE 11.313708498984761f
#define EPS 1e-12f

typedef __bf16 bf16x8 __attribute__((ext_vector_type(8)));
typedef float  f32x4  __attribute__((ext_vector_type(4)));

__device__ __forceinline__ f32x4 mfma16(bf16x8 a, bf16x8 b, f32x4 c) {
  return __builtin_amdgcn_mfma_f32_16x16x32_bf16(a, b, c, 0, 0, 0);
}

__device__ __forceinline__ float waveSum(float v) {
#pragma unroll
  for (int m = 32; m > 0; m >>= 1) v += __shfl_xor(v, m, 64);
  return v;
}

// async global->LDS DMA, 16B per lane, LDS dest = uniform base + lane*16
__device__ __forceinline__ void load_lds16(const void* g, void* l) {
  __builtin_amdgcn_global_load_lds(
      (const __attribute__((address_space(1))) uint32_t*)g,
      (__attribute__((address_space(3))) uint32_t*)l, 16, 0, 0);
}

// ---- ws layout (byte offsets) ----
// Wd bf16 [393216] (DMA-order tiled, see k_prep) : [0, 786432)
// bias2 f32 [128]          : [786432, 786944)
// fn bf16 [8192][128]      : [786944, 2884096)
// Zp f32 [2][4][32][256]   : [2884096, 3146240)
#define OFF_W    0
#define OFF_BIAS 786432
#define OFF_FN   786944
#define OFF_ZP   2884096

// Wd layout: for W[o][k] (o=0..127 output col, k=0..3071):
//   kt=k>>6, ks=(k>>5)&1, g=o>>4, lane=(o&15)+16*((k>>3)&3), e=k&7
//   Wd_bf16_idx = ((kt*16 + ks*8 + g)*64 + lane)*8 + e
// i.e. per BK=64 tile kt: 16 sub-tiles (ks,g), each 1 KB in DMA lane-order:
// lane quad*16+l15 holds the 16B = W[g*16+l15][kt*64+ks*32+quad*8 .. +7].

// ---------------- k_prep: Wd = fc1_w @ conv_w (blocks 0..191, o-half x k32)
//                  bias2[o] = fc1_w[o,:].conv_b + fc1_b[o] (blocks 192..319)
__global__ __launch_bounds__(256) void k_prep(const float* __restrict__ conv_w,
                                              const float* __restrict__ fc1_w,
                                              const float* __restrict__ conv_b,
                                              const float* __restrict__ fc1_b,
                                              __bf16* __restrict__ Wd,
                                              float* __restrict__ bias2,
                                              float* __restrict__ loss) {
  __shared__ float cw_s[64][36];    // [c][k], padded
  __shared__ float fc1_s[64][65];   // [o][c], padded
  __shared__ float red[4];
  const int t = threadIdx.x;
  if (blockIdx.x >= 192) {
    // ---- bias path ----
    const int o = blockIdx.x - 192;
    if (o == 0 && t == 0) loss[0] = 0.f;
    float p = fc1_w[o * 512 + t] * conv_b[t] +
              fc1_w[o * 512 + 256 + t] * conv_b[256 + t];
    p = waveSum(p);
    if ((t & 63) == 0) red[t >> 6] = p;
    __syncthreads();
    if (t == 0) bias2[o] = red[0] + red[1] + red[2] + red[3] + fc1_b[o];
    return;
  }
  // ---- fused-weight path: block = (o-half, k-chunk of 32) ----
  const int oh = blockIdx.x & 1;
  const int kt32 = blockIdx.x >> 1;  // 0..95
  const int k0 = kt32 * 32, o0 = oh * 64;
  const int og = t >> 3, kg = t & 7;  // thread tile: 2 o x 4 k
  float acc[2][4] = {};
  for (int cs = 0; cs < 8; ++cs) {
    const int cc = cs * 64;
    __syncthreads();
#pragma unroll
    for (int i = 0; i < 8; ++i) {
      int idx = t + 256 * i;
      int cr = idx >> 5, kk = idx & 31;
      cw_s[cr][kk] = conv_w[(cc + cr) * 3072 + k0 + kk];
    }
#pragma unroll
    for (int i = 0; i < 4; ++i) {
      int idx = t + 256 * i;
      int o = idx >> 4, c4 = (idx & 15) * 4;
      float4 v = *(const float4*)&fc1_w[(o0 + o) * 512 + cc + c4];
      fc1_s[o][c4 + 0] = v.x; fc1_s[o][c4 + 1] = v.y;
      fc1_s[o][c4 + 2] = v.z; fc1_s[o][c4 + 3] = v.w;
    }
    __syncthreads();
    for (int ci = 0; ci < 64; ++ci) {
      float4 cw = *(const float4*)&cw_s[ci][kg * 4];
#pragma unroll
      for (int j = 0; j < 2; ++j) {
        float fv = fc1_s[og * 2 + j][ci];
        acc[j][0] = fmaf(fv, cw.x, acc[j][0]);
        acc[j][1] = fmaf(fv, cw.y, acc[j][1]);
        acc[j][2] = fmaf(fv, cw.z, acc[j][2]);
        acc[j][3] = fmaf(fv, cw.w, acc[j][3]);
      }
    }
  }
#pragma unroll
  for (int j = 0; j < 2; ++j)
#pragma unroll
    for (int q = 0; q < 4; ++q) {
      const int o = o0 + og * 2 + j;
      const int k = k0 + kg * 4 + q;
      const int idx = (((k >> 6) * 16 + ((k >> 5) & 1) * 8 + (o >> 4)) * 64 +
                       (o & 15) + 16 * ((k >> 3) & 3)) * 8 + (k & 7);
      Wd[idx] = (__bf16)acc[j][q];
    }
}

// ---------------- k_gemm1f: LDS-staged A AND B, full K, fused epilogue -----
// 256 blocks x 256 thr (4 waves). Block = 32 rows x 128 cols x K=3072,
// 48 steps of BK=64. Per step per wave: 2 A-DMA + 4 B-DMA (global_load_lds),
// 12 ds_read_b128, 8 MFMA; ONE barrier per step (m97 2-phase structure).
// No B-in-VGPR double-buffer: R3-R5's VGPR_Count proved the allocator
// demotes it (needs 64-128 VGPR, got 40-100) into serialized load chains.
// A LDS [32][64] f32, XOR-swizzled 16B chunks (phys = log ^ (row&15));
// B LDS = 16 x 1KB sub-tiles in DMA lane-order (conflict-free by layout).
__global__ __launch_bounds__(256) void k_gemm1f(const float* __restrict__ x,
                                                const __bf16* __restrict__ Wd,
                                                const float* __restrict__ bias2,
                                                float* __restrict__ f,
                                                __bf16* __restrict__ fn) {
  __shared__ __align__(16) float A_lds[2][32 * 64];     // 2 x 8 KB
  __shared__ __align__(16) __bf16 B_lds[2][8192];       // 2 x 16 KB
  __shared__ float rsum[32][4];
  __shared__ float rinv[32];
  const int t = threadIdx.x;
  const int wave = t >> 6, lane = t & 63;
  const int l15 = lane & 15, quad = lane >> 4;
  const int m0 = blockIdx.x * 32;

  // A DMA mapping (2 insts/wave): inst jj=wave*2+j covers LDS f32
  // [jj*256 + lane*4 ..+3] -> row = jj*4 + (lane>>4), phys chunk cp = l15,
  // logical chunk cl = cp ^ (row&15), global col = cl*4.
  int dr[2], dc[2];
#pragma unroll
  for (int j = 0; j < 2; ++j) {
    int row = wave * 8 + j * 4 + (lane >> 4);
    int cl = (lane & 15) ^ (row & 15);
    dr[j] = row;
    dc[j] = cl * 4;
  }

  f32x4 acc[2][2] = {{{0.f,0.f,0.f,0.f},{0.f,0.f,0.f,0.f}},
                     {{0.f,0.f,0.f,0.f},{0.f,0.f,0.f,0.f}}};

  // stage K-tile kt into buffer buf
  auto stage = [&](int kt, int buf) {
#pragma unroll
    for (int j = 0; j < 2; ++j)
      load_lds16(x + (m0 + dr[j]) * 3072 + kt * 64 + dc[j],
                 &A_lds[buf][(wave * 2 + j) * 256]);
#pragma unroll
    for (int i = 0; i < 4; ++i) {
      int sidx = wave * 4 + i;  // sub-tile (ks = sidx>>3, g = sidx&7)
      load_lds16(Wd + ((kt * 16 + sidx) * 64 + lane) * 8,
                 &B_lds[buf][sidx * 512]);
    }
  };

  auto compute = [&](int buf) {
    const float* Abuf = &A_lds[buf][0];
    const __bf16* Bbuf = &B_lds[buf][0];
#pragma unroll
    for (int ks = 0; ks < 2; ++ks) {
      bf16x8 afrag[2];
#pragma unroll
      for (int mi = 0; mi < 2; ++mi) {
        const int rb = (l15 + mi * 16) * 64;
        float4 lo = *(const float4*)&Abuf[rb + (((ks * 8 + quad * 2 + 0) ^ l15) << 2)];
        float4 hi = *(const float4*)&Abuf[rb + (((ks * 8 + quad * 2 + 1) ^ l15) << 2)];
        union { __bf16 h[8]; bf16x8 v; } pk;
        pk.h[0] = (__bf16)lo.x; pk.h[1] = (__bf16)lo.y;
        pk.h[2] = (__bf16)lo.z; pk.h[3] = (__bf16)lo.w;
        pk.h[4] = (__bf16)hi.x; pk.h[5] = (__bf16)hi.y;
        pk.h[6] = (__bf16)hi.z; pk.h[7] = (__bf16)hi.w;
        afrag[mi] = pk.v;
      }
#pragma unroll
      for (int ni = 0; ni < 2; ++ni) {
        bf16x8 bfrag =
            *(const bf16x8*)&Bbuf[(ks * 8 + wave * 2 + ni) * 512 + lane * 8];
#pragma unroll
        for (int mi = 0; mi < 2; ++mi)
          acc[mi][ni] = mfma16(afrag[mi], bfrag, acc[mi][ni]);
      }
    }
  };

  stage(0, 0);
  for (int kt = 0; kt < 48; ++kt) {
    __syncthreads();  // DMA(kt) landed (vmcnt0); all reads of buf[kt&1] from
                      // step kt-2 are done -> safe to reuse below
    if (kt < 47) stage(kt + 1, (kt + 1) & 1);
    __builtin_amdgcn_sched_barrier(0);  // pin prefetch issue before compute
    compute(kt & 1);
  }

  // ---- fused finalize: bias, row L2-norm over 128 cols, write f + fn ----
  __syncthreads();
#pragma unroll
  for (int ni = 0; ni < 2; ++ni) {
    const float bv = bias2[wave * 32 + ni * 16 + l15];
#pragma unroll
    for (int mi = 0; mi < 2; ++mi)
#pragma unroll
      for (int r = 0; r < 4; ++r) acc[mi][ni][r] += bv;
  }
#pragma unroll
  for (int mi = 0; mi < 2; ++mi)
#pragma unroll
    for (int r = 0; r < 4; ++r) {
      float s = fmaf(acc[mi][0][r], acc[mi][0][r],
                     acc[mi][1][r] * acc[mi][1][r]);
      s += __shfl_xor(s, 1, 64);
      s += __shfl_xor(s, 2, 64);
      s += __shfl_xor(s, 4, 64);
      s += __shfl_xor(s, 8, 64);  // sum over l15 -> wave's 32 cols
      if (l15 == 0) rsum[mi * 16 + quad * 4 + r][wave] = s;
    }
  __syncthreads();
  if (t < 32)
    rinv[t] = 1.f / fmaxf(
        sqrtf(rsum[t][0] + rsum[t][1] + rsum[t][2] + rsum[t][3]), EPS);
  __syncthreads();
#pragma unroll
  for (int mi = 0; mi < 2; ++mi)
#pragma unroll
    for (int r = 0; r < 4; ++r) {
      const int row = mi * 16 + quad * 4 + r;
      const float iv = rinv[row];
#pragma unroll
      for (int ni = 0; ni < 2; ++ni) {
        const int g = (m0 + row) * 128 + wave * 32 + ni * 16 + l15;
        f[g] = acc[mi][ni][r];
        fn[g] = (__bf16)(acc[mi][ni][r] * iv);
      }
    }
}

// ---------------- A[b] = fn_b @ fn_b^T  +  fused Z column-partials ---------
// Zp[z][ti][b][m]: partial (over 64 rows of ti) column sums of E*(1-eye)*drop.
__global__ __launch_bounds__(256) void k_gemm2(const __bf16* __restrict__ fn,
                                               const float* __restrict__ d1,
                                               const float* __restrict__ d2,
                                               float* __restrict__ Aout,
                                               float* __restrict__ Zp) {
  __shared__ __align__(16) __bf16 Li[64][136];
  __shared__ __align__(16) __bf16 Lj[64][136];
  __shared__ float zred[2][4][64];
  const int t = threadIdx.x;
  const int b = blockIdx.y;
  const int ti = blockIdx.x >> 2, tj = blockIdx.x & 3;
  const int i0 = ti * 64, j0 = tj * 64;
  const int wave = t >> 6, lane = t & 63;
  const int l15 = lane & 15, quad = lane >> 4;
  const __bf16* fb = fn + b * 32768;
#pragma unroll
  for (int i = 0; i < 4; ++i) {
    int idx = t + 256 * i;
    int r = idx >> 4, c8 = (idx & 15) * 8;
    *(uint4*)&Li[r][c8] = *(const uint4*)&fb[(i0 + r) * 128 + c8];
    *(uint4*)&Lj[r][c8] = *(const uint4*)&fb[(j0 + r) * 128 + c8];
  }
  __syncthreads();
  f32x4 acc[4] = {{0.f, 0.f, 0.f, 0.f}, {0.f, 0.f, 0.f, 0.f},
                  {0.f, 0.f, 0.f, 0.f}, {0.f, 0.f, 0.f, 0.f}};
#pragma unroll
  for (int ks = 0; ks < 4; ++ks) {
    bf16x8 af = *(const bf16x8*)&Li[wave * 16 + l15][ks * 32 + quad * 8];
#pragma unroll
    for (int nt = 0; nt < 4; ++nt) {
      bf16x8 bf = *(const bf16x8*)&Lj[nt * 16 + l15][ks * 32 + quad * 8];
      acc[nt] = mfma16(af, bf, acc[nt]);
    }
  }
  const int base = b * 65536;
  float* Ab = Aout + base;
  float z1c[4] = {0.f, 0.f, 0.f, 0.f}, z2c[4] = {0.f, 0.f, 0.f, 0.f};
#pragma unroll
  for (int nt = 0; nt < 4; ++nt) {
    int gj = j0 + nt * 16 + l15;
#pragma unroll
    for (int r = 0; r < 4; ++r) {
      int gi = i0 + wave * 16 + quad * 4 + r;
      float a = acc[nt][r];
      Ab[gi * 256 + gj] = a;
      float e = __expf(fmaf(S_SCALE, a, -S_SCALE));
      if (gi != gj) {
        int idx = base + gi * 256 + gj;
        z1c[nt] = fmaf(e, d1[idx], z1c[nt]);
        z2c[nt] = fmaf(e, d2[idx], z2c[nt]);
      }
    }
  }
#pragma unroll
  for (int nt = 0; nt < 4; ++nt) {
    z1c[nt] += __shfl_xor(z1c[nt], 16, 64);
    z1c[nt] += __shfl_xor(z1c[nt], 32, 64);
    z2c[nt] += __shfl_xor(z2c[nt], 16, 64);
    z2c[nt] += __shfl_xor(z2c[nt], 32, 64);
  }
  if (quad == 0) {
#pragma unroll
    for (int nt = 0; nt < 4; ++nt) {
      zred[0][wave][nt * 16 + l15] = z1c[nt];
      zred[1][wave][nt * 16 + l15] = z2c[nt];
    }
  }
  __syncthreads();
  if (t < 128) {
    int z = t >> 6, c = t & 63;
    float s = zred[z][0][c] + zred[z][1][c] + zred[z][2][c] + zred[z][3][c];
    Zp[(z * 4 + ti) * 8192 + b * 256 + j0 + c] = s;
  }
}

// ---------------- loss = -1/8192 * sum E^2*d2[i,k]*d1[k,i]/(Z2[k]Z1[i]) ----
__global__ __launch_bounds__(256) void k_loss(const float* __restrict__ Aout,
                                              const float* __restrict__ d1,
                                              const float* __restrict__ d2,
                                              const float* __restrict__ Zp,
                                              float* __restrict__ loss) {
  __shared__ float d1s[64][65];  // d1[k][i] tile, transposed access
  __shared__ float z1s[64], z2s[64];
  __shared__ float red[4];
  const int t = threadIdx.x;
  const int b = blockIdx.y;
  const int ic = blockIdx.x >> 2, kc = blockIdx.x & 3;
  const int i0 = ic * 64, k0 = kc * 64;
  const int base = b * 65536;
  if (t < 64) {
    float s = 0.f;
#pragma unroll
    for (int p = 0; p < 4; ++p) s += Zp[p * 8192 + b * 256 + i0 + t];
    z1s[t] = 1.f / fmaxf(s, EPS);
  } else if (t < 128) {
    float s = 0.f;
#pragma unroll
    for (int p = 0; p < 4; ++p) s += Zp[(4 + p) * 8192 + b * 256 + k0 + t - 64];
    z2s[t - 64] = 1.f / fmaxf(s, EPS);
  }
#pragma unroll
  for (int ii = 0; ii < 16; ++ii) {
    int idx = t + 256 * ii;
    int kr = idx >> 6, ci = idx & 63;
    d1s[kr][ci] = d1[base + (k0 + kr) * 256 + i0 + ci];
  }
  __syncthreads();
  const int kl = t & 63, ig = t >> 6;
  float inv2 = z2s[kl];
  float accv = 0.f;
  for (int ii = 0; ii < 16; ++ii) {
    int il = ig * 16 + ii;
    int idx = base + (i0 + il) * 256 + k0 + kl;
    float a = Aout[idx];
    float e = __expf(fmaf(2.f * S_SCALE, a, -2.f * S_SCALE));
    float v = e * d2[idx] * d1s[kl][il] * z1s[il] * inv2;
    if (i0 + il != k0 + kl) accv += v;
  }
  accv = waveSum(accv);
  if ((t & 63) == 0) red[t >> 6] = accv;
  __syncthreads();
  if (t == 0) {
    float tot = red[0] + red[1] + red[2] + red[3];
    atomicAdd(loss, tot * (-1.f / 8192.f));
  }
}

extern "C" void kernel_launch(void* const* d_in, const int* in_sizes, int n_in,
                              void* d_out, int out_size, void* d_ws,
                              size_t ws_size, hipStream_t stream) {
  const float* x = (const float*)d_in[0];
  const float* conv_w = (const float*)d_in[1];
  const float* conv_b = (const float*)d_in[2];
  const float* fc1_w = (const float*)d_in[3];
  const float* fc1_b = (const float*)d_in[4];
  const float* drop1 = (const float*)d_in[5];
  const float* drop2 = (const float*)d_in[6];
  char* ws = (char*)d_ws;
  __bf16* Wd = (__bf16*)(ws + OFF_W);
  float* bias2 = (float*)(ws + OFF_BIAS);
  __bf16* fn = (__bf16*)(ws + OFF_FN);
  float* Zp = (float*)(ws + OFF_ZP);
  float* f = (float*)d_out;         // [8192,128]
  float* Aout = f + 1048576;        // [32,256,256]
  float* loss = f + 3145728;        // scalar

  k_prep<<<320, 256, 0, stream>>>(conv_w, fc1_w, conv_b, fc1_b, Wd, bias2, loss);
  k_gemm1f<<<256, 256, 0, stream>>>(x, Wd, bias2, f, fn);
  k_gemm2<<<dim3(16, 32), 256, 0, stream>>>(fn, drop1, drop2, Aout, Zp);
  k_loss<<<dim3(16, 32), 256, 0, stream>>>(Aout, drop1, drop2, Zp, loss);
}

// Round 7
// 244.012 us; speedup vs baseline: 1.2368x; 1.0078x over previous
//
#include <hip/hip_runtime.h>
#include <stdint.h>

#define S_SCALE 11.313708498984761f
#define EPS 1e-12f

typedef __bf16 bf16x8 __attribute__((ext_vector_type(8)));
typedef float  f32x4  __attribute__((ext_vector_type(4)));

__device__ __forceinline__ f32x4 mfma16(bf16x8 a, bf16x8 b, f32x4 c) {
  return __builtin_amdgcn_mfma_f32_16x16x32_bf16(a, b, c, 0, 0, 0);
}

__device__ __forceinline__ float waveSum(float v) {
#pragma unroll
  for (int m = 32; m > 0; m >>= 1) v += __shfl_xor(v, m, 64);
  return v;
}

// async global->LDS DMA, 16B per lane, LDS dest = uniform base + lane*16
__device__ __forceinline__ void load_lds16(const float* g, float* l) {
  __builtin_amdgcn_global_load_lds(
      (const __attribute__((address_space(1))) uint32_t*)g,
      (__attribute__((address_space(3))) uint32_t*)l, 16, 0, 0);
}

// ---- ws layout (byte offsets) ----
// W bf16 [128][3072]       : [0, 786432)
// bias2 f32 [128]          : [786432, 786944)
// fn bf16 [8192][128]      : [786944, 2884096)
// Zp f32 [2][4][32][256]   : [2884096, 3146240)
#define OFF_W    0
#define OFF_BIAS 786432
#define OFF_FN   786944
#define OFF_ZP   2884096

// ---------------- k_prep: W = fc1_w @ conv_w (blocks 0..95, k-chunks of 32)
//   bias2[o] = fc1_w[o,:].conv_b + fc1_b[o] (blocks 96..223), these blocks
//   also ZERO f (gemm1 accumulates into f with atomics) and loss.
__global__ __launch_bounds__(256) void k_prep(const float* __restrict__ conv_w,
                                              const float* __restrict__ fc1_w,
                                              const float* __restrict__ conv_b,
                                              const float* __restrict__ fc1_b,
                                              __bf16* __restrict__ W,
                                              float* __restrict__ bias2,
                                              float* __restrict__ f,
                                              float* __restrict__ loss) {
  __shared__ float cw_s[64][36];    // [c][k], padded
  __shared__ float fc1_s[128][65];  // [o][c], padded
  __shared__ float red[4];
  const int t = threadIdx.x;
  if (blockIdx.x >= 96) {
    // ---- bias + zero path ----
    const int o = blockIdx.x - 96;
    if (o == 0 && t == 0) loss[0] = 0.f;
    // zero 32KB of f per block (4 MB total over 128 blocks)
    float4* fz = (float4*)f + o * 2048;
#pragma unroll
    for (int i = 0; i < 8; ++i)
      fz[i * 256 + t] = make_float4(0.f, 0.f, 0.f, 0.f);
    float p = fc1_w[o * 512 + t] * conv_b[t] +
              fc1_w[o * 512 + 256 + t] * conv_b[256 + t];
    p = waveSum(p);
    if ((t & 63) == 0) red[t >> 6] = p;
    __syncthreads();
    if (t == 0) bias2[o] = red[0] + red[1] + red[2] + red[3] + fc1_b[o];
    return;
  }
  // ---- fused-weight path: W[o][k] = sum_c fc1_w[o][c] * conv_w[c][k] ----
  const int kt = blockIdx.x;
  const int k0 = kt * 32;
  const int og = t >> 3, kg = t & 7;  // thread tile: 4 o x 4 k
  float acc[4][4] = {};
  for (int cs = 0; cs < 8; ++cs) {
    const int cc = cs * 64;
    __syncthreads();
#pragma unroll
    for (int i = 0; i < 8; ++i) {
      int idx = t + 256 * i;
      int cr = idx >> 5, kk = idx & 31;
      cw_s[cr][kk] = conv_w[(cc + cr) * 3072 + k0 + kk];
    }
#pragma unroll
    for (int i = 0; i < 8; ++i) {
      int idx = t + 256 * i;
      int o = idx >> 4, c4 = (idx & 15) * 4;
      float4 v = *(const float4*)&fc1_w[o * 512 + cc + c4];
      fc1_s[o][c4 + 0] = v.x; fc1_s[o][c4 + 1] = v.y;
      fc1_s[o][c4 + 2] = v.z; fc1_s[o][c4 + 3] = v.w;
    }
    __syncthreads();
    for (int ci = 0; ci < 64; ++ci) {
      float4 cw = *(const float4*)&cw_s[ci][kg * 4];
#pragma unroll
      for (int j = 0; j < 4; ++j) {
        float fv = fc1_s[og * 4 + j][ci];
        acc[j][0] = fmaf(fv, cw.x, acc[j][0]);
        acc[j][1] = fmaf(fv, cw.y, acc[j][1]);
        acc[j][2] = fmaf(fv, cw.z, acc[j][2]);
        acc[j][3] = fmaf(fv, cw.w, acc[j][3]);
      }
    }
  }
#pragma unroll
  for (int j = 0; j < 4; ++j)
#pragma unroll
    for (int q = 0; q < 4; ++q)
      W[(og * 4 + j) * 3072 + k0 + kg * 4 + q] = (__bf16)acc[j][q];
}

// ---------------- gemm1 helpers (R1-verified bodies) -----------------------
__device__ __forceinline__ void stageA(const float* __restrict__ x,
                                       float* __restrict__ lds, int wave,
                                       const int dr[2], const int dc[2],
                                       int m0, int k0) {
#pragma unroll
  for (int j = 0; j < 2; ++j)
    load_lds16(x + (m0 + dr[j]) * 3072 + k0 + dc[j],
               lds + (wave * 2 + j) * 256);
}

__device__ __forceinline__ void loadB(const __bf16* __restrict__ bp, int k0,
                                      uint4 (&dst)[2][2]) {
#pragma unroll
  for (int ks = 0; ks < 2; ++ks)
#pragma unroll
    for (int ni = 0; ni < 2; ++ni)
      dst[ks][ni] = *(const uint4*)(bp + ni * 16 * 3072 + k0 + ks * 32);
}

__device__ __forceinline__ void computeTile(const float* __restrict__ Abuf,
                                            const uint4 (&breg)[2][2],
                                            int l15, int quad,
                                            f32x4 (&acc)[2][2]) {
#pragma unroll
  for (int ks = 0; ks < 2; ++ks) {
    bf16x8 afrag[2];
#pragma unroll
    for (int mi = 0; mi < 2; ++mi) {
      const int rb = (l15 + mi * 16) * 64;
      float4 lo = *(const float4*)&Abuf[rb + (((ks * 8 + quad * 2 + 0) ^ l15) << 2)];
      float4 hi = *(const float4*)&Abuf[rb + (((ks * 8 + quad * 2 + 1) ^ l15) << 2)];
      union { __bf16 h[8]; bf16x8 v; } pk;
      pk.h[0] = (__bf16)lo.x; pk.h[1] = (__bf16)lo.y;
      pk.h[2] = (__bf16)lo.z; pk.h[3] = (__bf16)lo.w;
      pk.h[4] = (__bf16)hi.x; pk.h[5] = (__bf16)hi.y;
      pk.h[6] = (__bf16)hi.z; pk.h[7] = (__bf16)hi.w;
      afrag[mi] = pk.v;
    }
#pragma unroll
    for (int mi = 0; mi < 2; ++mi)
#pragma unroll
      for (int ni = 0; ni < 2; ++ni)
        acc[mi][ni] = mfma16(afrag[mi], *(const bf16x8*)&breg[ks][ni],
                             acc[mi][ni]);
  }
}

// ---------------- k_gemm1: split-K=4, atomic accumulate into f -------------
// grid (256, 4) x 256 thr = 1024 blocks -> 4 blocks/CU (16 waves/CU).
// Block = 32 rows x 128 cols x K=768 (12 steps of BK=64). Empirical law from
// R1/R3/R5/R6: dur ~ steps_per_block / blocks_per_CU; this minimizes both.
// A LDS XOR-swizzled in 16B chunks: phys_chunk = log_chunk ^ (row&15).
__global__ __launch_bounds__(256, 4) void k_gemm1(const float* __restrict__ x,
                                                  const __bf16* __restrict__ W,
                                                  float* __restrict__ f) {
  __shared__ __align__(16) float A_lds[2][2048];  // 2 x 8 KB
  const int t = threadIdx.x;
  const int wave = t >> 6, lane = t & 63;
  const int l15 = lane & 15, quad = lane >> 4;
  const int m0 = blockIdx.x * 32;
  const int kbase = blockIdx.y * 768;

  // DMA source mapping (2 insts/wave): inst jj=wave*2+j covers LDS fp32
  // [jj*256 + lane*4 ..+3] -> row = jj*4 + lane/16, phys chunk cp = lane%16,
  // logical chunk cl = cp ^ (row&15), global col = cl*4.
  int dr[2], dc[2];
#pragma unroll
  for (int j = 0; j < 2; ++j) {
    int row = wave * 8 + j * 4 + (lane >> 4);
    int cl = (lane & 15) ^ (row & 15);
    dr[j] = row;
    dc[j] = cl * 4;
  }

  f32x4 acc[2][2] = {{{0.f,0.f,0.f,0.f},{0.f,0.f,0.f,0.f}},
                     {{0.f,0.f,0.f,0.f},{0.f,0.f,0.f,0.f}}};
  const __bf16* bp = W + (wave * 32 + l15) * 3072 + quad * 8;

  uint4 bA[2][2], bB[2][2];
  // prologue: tile 0 -> buf0 / bA
  stageA(x, &A_lds[0][0], wave, dr, dc, m0, kbase);
  loadB(bp, kbase, bA);
  __syncthreads();  // vmcnt(0): A0 in LDS, B0 in regs

  for (int it2 = 0; it2 < 6; ++it2) {
    const int itA = it2 * 2;
    // ---- phase A: compute tile itA (buf0/bA), prefetch itA+1 -> buf1/bB ----
    stageA(x, &A_lds[1][0], wave, dr, dc, m0, kbase + (itA + 1) * 64);
    loadB(bp, kbase + (itA + 1) * 64, bB);
    __builtin_amdgcn_sched_barrier(0);  // pin prefetch issue before compute
    computeTile(&A_lds[0][0], bA, l15, quad, acc);
    __syncthreads();  // drain: tile itA+1 ready
    // ---- phase B: compute tile itA+1 (buf1/bB), prefetch itA+2 -> buf0/bA --
    if (it2 < 5) {
      stageA(x, &A_lds[0][0], wave, dr, dc, m0, kbase + (itA + 2) * 64);
      loadB(bp, kbase + (itA + 2) * 64, bA);
    }
    __builtin_amdgcn_sched_barrier(0);
    computeTile(&A_lds[1][0], bB, l15, quad, acc);
    __syncthreads();
  }

  // epilogue: atomic accumulate this K-quarter's partial into f
#pragma unroll
  for (int mi = 0; mi < 2; ++mi)
#pragma unroll
    for (int ni = 0; ni < 2; ++ni) {
      int col = wave * 32 + ni * 16 + l15;
#pragma unroll
      for (int r = 0; r < 4; ++r) {
        int row = m0 + mi * 16 + quad * 4 + r;
        atomicAdd(&f[row * 128 + col], acc[mi][ni][r]);
      }
    }
}

// ---------------- finalize: f += bias, row L2-norm -> fn bf16 --------------
// grid 2048 x 256: wave handles one row; f read (full sum) and rewritten.
__global__ __launch_bounds__(256) void k_fin(float* __restrict__ f_inout,
                                             const float* __restrict__ bias2,
                                             __bf16* __restrict__ fn) {
  const int wave = threadIdx.x >> 6, lane = threadIdx.x & 63;
  const int row = blockIdx.x * 4 + wave;
  const int i0 = row * 128 + lane, i1 = i0 + 64;
  float v0 = f_inout[i0] + bias2[lane];
  float v1 = f_inout[i1] + bias2[lane + 64];
  float ss = waveSum(fmaf(v0, v0, v1 * v1));
  float inv = 1.f / fmaxf(sqrtf(ss), EPS);
  f_inout[i0] = v0;
  f_inout[i1] = v1;
  fn[i0] = (__bf16)(v0 * inv);
  fn[i1] = (__bf16)(v1 * inv);
}

// ---------------- A[b] = fn_b @ fn_b^T  +  fused Z column-partials ---------
// Zp[z][ti][b][m]: partial (over 64 rows of ti) column sums of E*(1-eye)*drop.
__global__ __launch_bounds__(256) void k_gemm2(const __bf16* __restrict__ fn,
                                               const float* __restrict__ d1,
                                               const float* __restrict__ d2,
                                               float* __restrict__ Aout,
                                               float* __restrict__ Zp) {
  __shared__ __align__(16) __bf16 Li[64][136];
  __shared__ __align__(16) __bf16 Lj[64][136];
  __shared__ float zred[2][4][64];
  const int t = threadIdx.x;
  const int b = blockIdx.y;
  const int ti = blockIdx.x >> 2, tj = blockIdx.x & 3;
  const int i0 = ti * 64, j0 = tj * 64;
  const int wave = t >> 6, lane = t & 63;
  const int l15 = lane & 15, quad = lane >> 4;
  const __bf16* fb = fn + b * 32768;
#pragma unroll
  for (int i = 0; i < 4; ++i) {
    int idx = t + 256 * i;
    int r = idx >> 4, c8 = (idx & 15) * 8;
    *(uint4*)&Li[r][c8] = *(const uint4*)&fb[(i0 + r) * 128 + c8];
    *(uint4*)&Lj[r][c8] = *(const uint4*)&fb[(j0 + r) * 128 + c8];
  }
  __syncthreads();
  f32x4 acc[4] = {{0.f, 0.f, 0.f, 0.f}, {0.f, 0.f, 0.f, 0.f},
                  {0.f, 0.f, 0.f, 0.f}, {0.f, 0.f, 0.f, 0.f}};
#pragma unroll
  for (int ks = 0; ks < 4; ++ks) {
    bf16x8 af = *(const bf16x8*)&Li[wave * 16 + l15][ks * 32 + quad * 8];
#pragma unroll
    for (int nt = 0; nt < 4; ++nt) {
      bf16x8 bf = *(const bf16x8*)&Lj[nt * 16 + l15][ks * 32 + quad * 8];
      acc[nt] = mfma16(af, bf, acc[nt]);
    }
  }
  const int base = b * 65536;
  float* Ab = Aout + base;
  float z1c[4] = {0.f, 0.f, 0.f, 0.f}, z2c[4] = {0.f, 0.f, 0.f, 0.f};
#pragma unroll
  for (int nt = 0; nt < 4; ++nt) {
    int gj = j0 + nt * 16 + l15;
#pragma unroll
    for (int r = 0; r < 4; ++r) {
      int gi = i0 + wave * 16 + quad * 4 + r;
      float a = acc[nt][r];
      Ab[gi * 256 + gj] = a;
      float e = __expf(fmaf(S_SCALE, a, -S_SCALE));
      if (gi != gj) {
        int idx = base + gi * 256 + gj;
        z1c[nt] = fmaf(e, d1[idx], z1c[nt]);
        z2c[nt] = fmaf(e, d2[idx], z2c[nt]);
      }
    }
  }
#pragma unroll
  for (int nt = 0; nt < 4; ++nt) {
    z1c[nt] += __shfl_xor(z1c[nt], 16, 64);
    z1c[nt] += __shfl_xor(z1c[nt], 32, 64);
    z2c[nt] += __shfl_xor(z2c[nt], 16, 64);
    z2c[nt] += __shfl_xor(z2c[nt], 32, 64);
  }
  if (quad == 0) {
#pragma unroll
    for (int nt = 0; nt < 4; ++nt) {
      zred[0][wave][nt * 16 + l15] = z1c[nt];
      zred[1][wave][nt * 16 + l15] = z2c[nt];
    }
  }
  __syncthreads();
  if (t < 128) {
    int z = t >> 6, c = t & 63;
    float s = zred[z][0][c] + zred[z][1][c] + zred[z][2][c] + zred[z][3][c];
    Zp[(z * 4 + ti) * 8192 + b * 256 + j0 + c] = s;
  }
}

// ---------------- loss = -1/8192 * sum E^2*d2[i,k]*d1[k,i]/(Z2[k]Z1[i]) ----
__global__ __launch_bounds__(256) void k_loss(const float* __restrict__ Aout,
                                              const float* __restrict__ d1,
                                              const float* __restrict__ d2,
                                              const float* __restrict__ Zp,
                                              float* __restrict__ loss) {
  __shared__ float d1s[64][65];  // d1[k][i] tile, transposed access
  __shared__ float z1s[64], z2s[64];
  __shared__ float red[4];
  const int t = threadIdx.x;
  const int b = blockIdx.y;
  const int ic = blockIdx.x >> 2, kc = blockIdx.x & 3;
  const int i0 = ic * 64, k0 = kc * 64;
  const int base = b * 65536;
  if (t < 64) {
    float s = 0.f;
#pragma unroll
    for (int p = 0; p < 4; ++p) s += Zp[p * 8192 + b * 256 + i0 + t];
    z1s[t] = 1.f / fmaxf(s, EPS);
  } else if (t < 128) {
    float s = 0.f;
#pragma unroll
    for (int p = 0; p < 4; ++p) s += Zp[(4 + p) * 8192 + b * 256 + k0 + t - 64];
    z2s[t - 64] = 1.f / fmaxf(s, EPS);
  }
#pragma unroll
  for (int ii = 0; ii < 16; ++ii) {
    int idx = t + 256 * ii;
    int kr = idx >> 6, ci = idx & 63;
    d1s[kr][ci] = d1[base + (k0 + kr) * 256 + i0 + ci];
  }
  __syncthreads();
  const int kl = t & 63, ig = t >> 6;
  float inv2 = z2s[kl];
  float accv = 0.f;
  for (int ii = 0; ii < 16; ++ii) {
    int il = ig * 16 + ii;
    int idx = base + (i0 + il) * 256 + k0 + kl;
    float a = Aout[idx];
    float e = __expf(fmaf(2.f * S_SCALE, a, -2.f * S_SCALE));
    float v = e * d2[idx] * d1s[kl][il] * z1s[il] * inv2;
    if (i0 + il != k0 + kl) accv += v;
  }
  accv = waveSum(accv);
  if ((t & 63) == 0) red[t >> 6] = accv;
  __syncthreads();
  if (t == 0) {
    float tot = red[0] + red[1] + red[2] + red[3];
    atomicAdd(loss, tot * (-1.f / 8192.f));
  }
}

extern "C" void kernel_launch(void* const* d_in, const int* in_sizes, int n_in,
                              void* d_out, int out_size, void* d_ws,
                              size_t ws_size, hipStream_t stream) {
  const float* x = (const float*)d_in[0];
  const float* conv_w = (const float*)d_in[1];
  const float* conv_b = (const float*)d_in[2];
  const float* fc1_w = (const float*)d_in[3];
  const float* fc1_b = (const float*)d_in[4];
  const float* drop1 = (const float*)d_in[5];
  const float* drop2 = (const float*)d_in[6];
  char* ws = (char*)d_ws;
  __bf16* W = (__bf16*)(ws + OFF_W);
  float* bias2 = (float*)(ws + OFF_BIAS);
  __bf16* fn = (__bf16*)(ws + OFF_FN);
  float* Zp = (float*)(ws + OFF_ZP);
  float* f = (float*)d_out;         // [8192,128]
  float* Aout = f + 1048576;        // [32,256,256]
  float* loss = f + 3145728;        // scalar

  k_prep<<<224, 256, 0, stream>>>(conv_w, fc1_w, conv_b, fc1_b, W, bias2, f,
                                  loss);
  k_gemm1<<<dim3(256, 4), 256, 0, stream>>>(x, W, f);
  k_fin<<<2048, 256, 0, stream>>>(f, bias2, fn);
  k_gemm2<<<dim3(16, 32), 256, 0, stream>>>(fn, drop1, drop2, Aout, Zp);
  k_loss<<<dim3(16, 32), 256, 0, stream>>>(Aout, drop1, drop2, Zp, loss);
}

// Round 8
// 235.952 us; speedup vs baseline: 1.2791x; 1.0342x over previous
//
#include <hip/hip_runtime.h>
#include <stdint.h>

#define S_SCALE 11.313708498984761f
#define EPS 1e-12f

typedef __bf16 bf16x8 __attribute__((ext_vector_type(8)));
typedef float  f32x4  __attribute__((ext_vector_type(4)));

__device__ __forceinline__ f32x4 mfma16(bf16x8 a, bf16x8 b, f32x4 c) {
  return __builtin_amdgcn_mfma_f32_16x16x32_bf16(a, b, c, 0, 0, 0);
}

__device__ __forceinline__ float waveSum(float v) {
#pragma unroll
  for (int m = 32; m > 0; m >>= 1) v += __shfl_xor(v, m, 64);
  return v;
}

// async global->LDS DMA, 16B per lane, LDS dest = uniform base + lane*16
__device__ __forceinline__ void load_lds16(const void* g, void* l) {
  __builtin_amdgcn_global_load_lds(
      (const __attribute__((address_space(1))) uint32_t*)g,
      (__attribute__((address_space(3))) uint32_t*)l, 16, 0, 0);
}

// ---- ws layout (byte offsets) ----
// W bf16 [128][3072]       : [0, 786432)
// bias2 f32 [128]          : [786432, 786944)
// fn bf16 [8192][128]      : [786944, 2884096)
// Zp f32 [2][4][32][256]   : [2884096, 3146240)
// P1..P3 f32 [3][8192][128]: [3146240, 15729152)
#define OFF_W    0
#define OFF_BIAS 786432
#define OFF_FN   786944
#define OFF_ZP   2884096
#define OFF_P    3146240

// ---------------- k_prep: W = fc1_w @ conv_w (blocks 0..95, k-chunks of 32)
//                  bias2[o] = fc1_w[o,:].conv_b + fc1_b[o] (blocks 96..223)
__global__ __launch_bounds__(256) void k_prep(const float* __restrict__ conv_w,
                                              const float* __restrict__ fc1_w,
                                              const float* __restrict__ conv_b,
                                              const float* __restrict__ fc1_b,
                                              __bf16* __restrict__ W,
                                              float* __restrict__ bias2,
                                              float* __restrict__ loss) {
  __shared__ float cw_s[64][36];    // [c][k], padded
  __shared__ float fc1_s[128][65];  // [o][c], padded
  __shared__ float red[4];
  const int t = threadIdx.x;
  if (blockIdx.x >= 96) {
    // ---- bias path ----
    const int o = blockIdx.x - 96;
    if (o == 0 && t == 0) loss[0] = 0.f;
    float p = fc1_w[o * 512 + t] * conv_b[t] +
              fc1_w[o * 512 + 256 + t] * conv_b[256 + t];
    p = waveSum(p);
    if ((t & 63) == 0) red[t >> 6] = p;
    __syncthreads();
    if (t == 0) bias2[o] = red[0] + red[1] + red[2] + red[3] + fc1_b[o];
    return;
  }
  // ---- fused-weight path: W[o][k] = sum_c fc1_w[o][c] * conv_w[c][k] ----
  const int kt = blockIdx.x;
  const int k0 = kt * 32;
  const int og = t >> 3, kg = t & 7;  // thread tile: 4 o x 4 k
  float acc[4][4] = {};
  for (int cs = 0; cs < 8; ++cs) {
    const int cc = cs * 64;
    __syncthreads();
#pragma unroll
    for (int i = 0; i < 8; ++i) {
      int idx = t + 256 * i;
      int cr = idx >> 5, kk = idx & 31;
      cw_s[cr][kk] = conv_w[(cc + cr) * 3072 + k0 + kk];
    }
#pragma unroll
    for (int i = 0; i < 8; ++i) {
      int idx = t + 256 * i;
      int o = idx >> 4, c4 = (idx & 15) * 4;
      float4 v = *(const float4*)&fc1_w[o * 512 + cc + c4];
      fc1_s[o][c4 + 0] = v.x; fc1_s[o][c4 + 1] = v.y;
      fc1_s[o][c4 + 2] = v.z; fc1_s[o][c4 + 3] = v.w;
    }
    __syncthreads();
    for (int ci = 0; ci < 64; ++ci) {
      float4 cw = *(const float4*)&cw_s[ci][kg * 4];
#pragma unroll
      for (int j = 0; j < 4; ++j) {
        float fv = fc1_s[og * 4 + j][ci];
        acc[j][0] = fmaf(fv, cw.x, acc[j][0]);
        acc[j][1] = fmaf(fv, cw.y, acc[j][1]);
        acc[j][2] = fmaf(fv, cw.z, acc[j][2]);
        acc[j][3] = fmaf(fv, cw.w, acc[j][3]);
      }
    }
  }
#pragma unroll
  for (int j = 0; j < 4; ++j)
#pragma unroll
    for (int q = 0; q < 4; ++q)
      W[(og * 4 + j) * 3072 + k0 + kg * 4 + q] = (__bf16)acc[j][q];
}

// ---------------- k_gemm1: BM=64 x BN=128, split-K=4, LDS-staged A and B ---
// grid (128, 4) x 256 thr = 512 blocks -> 2 blocks/CU. 12 steps of BK=64.
// 4 waves as 2M x 2N; wave tile 32 rows x 64 cols (acc[2][4] = 16 MFMA/step).
// Per wave-step: 8 DMA (4 A + 4 B) -> 2x better MFMA:staging than R7; W
// ingress = (8192/64)*786KB = 100 MB (was 201). Plain partial stores (P0=f).
// A LDS [64][64] f32, XOR-swizzled 16B chunks: phys = log ^ (row&15).
// B LDS [128][64] bf16, XOR-swizzled 16B chunks: phys = log ^ (o&7)
//   (write side pre-swizzles the GLOBAL k-offset; both-sides-or-neither).
__global__ __launch_bounds__(256, 2) void k_gemm1(const float* __restrict__ x,
                                                  const __bf16* __restrict__ W,
                                                  float* __restrict__ f,
                                                  float* __restrict__ P123) {
  __shared__ __align__(16) float A_lds[2][64 * 64];     // 2 x 16 KB
  __shared__ __align__(16) __bf16 B_lds[2][128 * 64];   // 2 x 16 KB
  const int t = threadIdx.x;
  const int wave = t >> 6, lane = t & 63;
  const int wm = wave >> 1, wn = wave & 1;
  const int l15 = lane & 15, quad = lane >> 4;
  const int m0 = blockIdx.x * 64;
  const int q = blockIdx.y;            // K-quarter
  const int kbase = q * 768;
  float* P = q == 0 ? f : P123 + (q - 1) * 1048576;

  // A DMA mapping (4 insts/wave): inst jj=wave*4+j covers LDS f32
  // [jj*256 + lane*4 ..+3] -> row = jj*4 + (lane>>4), phys chunk cp = l15,
  // logical chunk cl = cp ^ (row&15), global col = cl*4.
  int adr[4], adc[4];
#pragma unroll
  for (int j = 0; j < 4; ++j) {
    int row = (wave * 4 + j) * 4 + (lane >> 4);
    adr[j] = row;
    adc[j] = ((lane & 15) ^ (row & 15)) * 4;
  }
  // B DMA mapping (4 insts/wave): inst jj=wave*4+j covers o = jj*8+(lane>>3),
  // phys chunk = lane&7 at LDS row o -> logical = (lane&7)^(o&7), gk = log*8.
  int bo[4], bk[4];
#pragma unroll
  for (int j = 0; j < 4; ++j) {
    int o = (wave * 4 + j) * 8 + (lane >> 3);
    bo[j] = o;
    bk[j] = ((lane & 7) ^ (o & 7)) * 8;
  }

  f32x4 acc[2][4] = {};

  auto stage = [&](int kt, int buf) {
    const int k0 = kbase + kt * 64;
#pragma unroll
    for (int j = 0; j < 4; ++j)
      load_lds16(x + (m0 + adr[j]) * 3072 + k0 + adc[j],
                 &A_lds[buf][(wave * 4 + j) * 256]);
#pragma unroll
    for (int j = 0; j < 4; ++j)
      load_lds16(W + bo[j] * 3072 + k0 + bk[j],
                 &B_lds[buf][(wave * 4 + j) * 512]);
  };

  auto compute = [&](int buf) {
    const float* Abuf = &A_lds[buf][0];
    const __bf16* Bbuf = &B_lds[buf][0];
#pragma unroll
    for (int ks = 0; ks < 2; ++ks) {
      bf16x8 afrag[2];
#pragma unroll
      for (int mi = 0; mi < 2; ++mi) {
        const int rb = (wm * 32 + mi * 16 + l15) * 64;
        float4 lo = *(const float4*)&Abuf[rb + (((ks * 8 + quad * 2 + 0) ^ l15) << 2)];
        float4 hi = *(const float4*)&Abuf[rb + (((ks * 8 + quad * 2 + 1) ^ l15) << 2)];
        union { __bf16 h[8]; bf16x8 v; } pk;
        pk.h[0] = (__bf16)lo.x; pk.h[1] = (__bf16)lo.y;
        pk.h[2] = (__bf16)lo.z; pk.h[3] = (__bf16)lo.w;
        pk.h[4] = (__bf16)hi.x; pk.h[5] = (__bf16)hi.y;
        pk.h[6] = (__bf16)hi.z; pk.h[7] = (__bf16)hi.w;
        afrag[mi] = pk.v;
      }
#pragma unroll
      for (int ni = 0; ni < 4; ++ni) {
        const int o = wn * 64 + ni * 16 + l15;
        bf16x8 bfrag =
            *(const bf16x8*)&Bbuf[o * 64 + (((ks * 4 + quad) ^ (o & 7)) << 3)];
#pragma unroll
        for (int mi = 0; mi < 2; ++mi)
          acc[mi][ni] = mfma16(afrag[mi], bfrag, acc[mi][ni]);
      }
    }
  };

  stage(0, 0);
  __syncthreads();
  for (int kt = 0; kt < 12; ++kt) {
    if (kt < 11) stage(kt + 1, (kt + 1) & 1);
    __builtin_amdgcn_sched_barrier(0);  // pin prefetch issue before compute
    compute(kt & 1);
    __syncthreads();  // stage(kt+1) landed; reads of buf kt&1 done
  }

  // epilogue: plain partial store for this K-quarter
#pragma unroll
  for (int mi = 0; mi < 2; ++mi)
#pragma unroll
    for (int ni = 0; ni < 4; ++ni) {
      const int col = wn * 64 + ni * 16 + l15;
#pragma unroll
      for (int r = 0; r < 4; ++r) {
        const int row = m0 + wm * 32 + mi * 16 + quad * 4 + r;
        P[row * 128 + col] = acc[mi][ni][r];
      }
    }
}

// ---------------- finalize: f = sum of 4 partials + bias, L2-norm -> fn ----
// grid 2048 x 256: wave handles one row; f (=P0) read and rewritten in place.
__global__ __launch_bounds__(256) void k_fin(float* __restrict__ f_inout,
                                             const float* __restrict__ P123,
                                             const float* __restrict__ bias2,
                                             __bf16* __restrict__ fn) {
  const int wave = threadIdx.x >> 6, lane = threadIdx.x & 63;
  const int row = blockIdx.x * 4 + wave;
  const int i0 = row * 128 + lane, i1 = i0 + 64;
  float v0 = f_inout[i0] + P123[i0] + P123[1048576 + i0] +
             P123[2097152 + i0] + bias2[lane];
  float v1 = f_inout[i1] + P123[i1] + P123[1048576 + i1] +
             P123[2097152 + i1] + bias2[lane + 64];
  float ss = waveSum(fmaf(v0, v0, v1 * v1));
  float inv = 1.f / fmaxf(sqrtf(ss), EPS);
  f_inout[i0] = v0;
  f_inout[i1] = v1;
  fn[i0] = (__bf16)(v0 * inv);
  fn[i1] = (__bf16)(v1 * inv);
}

// ---------------- A[b] = fn_b @ fn_b^T  +  fused Z column-partials ---------
// Zp[z][ti][b][m]: partial (over 64 rows of ti) column sums of E*(1-eye)*drop.
__global__ __launch_bounds__(256) void k_gemm2(const __bf16* __restrict__ fn,
                                               const float* __restrict__ d1,
                                               const float* __restrict__ d2,
                                               float* __restrict__ Aout,
                                               float* __restrict__ Zp) {
  __shared__ __align__(16) __bf16 Li[64][136];
  __shared__ __align__(16) __bf16 Lj[64][136];
  __shared__ float zred[2][4][64];
  const int t = threadIdx.x;
  const int b = blockIdx.y;
  const int ti = blockIdx.x >> 2, tj = blockIdx.x & 3;
  const int i0 = ti * 64, j0 = tj * 64;
  const int wave = t >> 6, lane = t & 63;
  const int l15 = lane & 15, quad = lane >> 4;
  const __bf16* fb = fn + b * 32768;
#pragma unroll
  for (int i = 0; i < 4; ++i) {
    int idx = t + 256 * i;
    int r = idx >> 4, c8 = (idx & 15) * 8;
    *(uint4*)&Li[r][c8] = *(const uint4*)&fb[(i0 + r) * 128 + c8];
    *(uint4*)&Lj[r][c8] = *(const uint4*)&fb[(j0 + r) * 128 + c8];
  }
  __syncthreads();
  f32x4 acc[4] = {{0.f, 0.f, 0.f, 0.f}, {0.f, 0.f, 0.f, 0.f},
                  {0.f, 0.f, 0.f, 0.f}, {0.f, 0.f, 0.f, 0.f}};
#pragma unroll
  for (int ks = 0; ks < 4; ++ks) {
    bf16x8 af = *(const bf16x8*)&Li[wave * 16 + l15][ks * 32 + quad * 8];
#pragma unroll
    for (int nt = 0; nt < 4; ++nt) {
      bf16x8 bf = *(const bf16x8*)&Lj[nt * 16 + l15][ks * 32 + quad * 8];
      acc[nt] = mfma16(af, bf, acc[nt]);
    }
  }
  const int base = b * 65536;
  float* Ab = Aout + base;
  float z1c[4] = {0.f, 0.f, 0.f, 0.f}, z2c[4] = {0.f, 0.f, 0.f, 0.f};
#pragma unroll
  for (int nt = 0; nt < 4; ++nt) {
    int gj = j0 + nt * 16 + l15;
#pragma unroll
    for (int r = 0; r < 4; ++r) {
      int gi = i0 + wave * 16 + quad * 4 + r;
      float a = acc[nt][r];
      Ab[gi * 256 + gj] = a;
      float e = __expf(fmaf(S_SCALE, a, -S_SCALE));
      if (gi != gj) {
        int idx = base + gi * 256 + gj;
        z1c[nt] = fmaf(e, d1[idx], z1c[nt]);
        z2c[nt] = fmaf(e, d2[idx], z2c[nt]);
      }
    }
  }
#pragma unroll
  for (int nt = 0; nt < 4; ++nt) {
    z1c[nt] += __shfl_xor(z1c[nt], 16, 64);
    z1c[nt] += __shfl_xor(z1c[nt], 32, 64);
    z2c[nt] += __shfl_xor(z2c[nt], 16, 64);
    z2c[nt] += __shfl_xor(z2c[nt], 32, 64);
  }
  if (quad == 0) {
#pragma unroll
    for (int nt = 0; nt < 4; ++nt) {
      zred[0][wave][nt * 16 + l15] = z1c[nt];
      zred[1][wave][nt * 16 + l15] = z2c[nt];
    }
  }
  __syncthreads();
  if (t < 128) {
    int z = t >> 6, c = t & 63;
    float s = zred[z][0][c] + zred[z][1][c] + zred[z][2][c] + zred[z][3][c];
    Zp[(z * 4 + ti) * 8192 + b * 256 + j0 + c] = s;
  }
}

// ---------------- loss = -1/8192 * sum E^2*d2[i,k]*d1[k,i]/(Z2[k]Z1[i]) ----
__global__ __launch_bounds__(256) void k_loss(const float* __restrict__ Aout,
                                              const float* __restrict__ d1,
                                              const float* __restrict__ d2,
                                              const float* __restrict__ Zp,
                                              float* __restrict__ loss) {
  __shared__ float d1s[64][65];  // d1[k][i] tile, transposed access
  __shared__ float z1s[64], z2s[64];
  __shared__ float red[4];
  const int t = threadIdx.x;
  const int b = blockIdx.y;
  const int ic = blockIdx.x >> 2, kc = blockIdx.x & 3;
  const int i0 = ic * 64, k0 = kc * 64;
  const int base = b * 65536;
  if (t < 64) {
    float s = 0.f;
#pragma unroll
    for (int p = 0; p < 4; ++p) s += Zp[p * 8192 + b * 256 + i0 + t];
    z1s[t] = 1.f / fmaxf(s, EPS);
  } else if (t < 128) {
    float s = 0.f;
#pragma unroll
    for (int p = 0; p < 4; ++p) s += Zp[(4 + p) * 8192 + b * 256 + k0 + t - 64];
    z2s[t - 64] = 1.f / fmaxf(s, EPS);
  }
#pragma unroll
  for (int ii = 0; ii < 16; ++ii) {
    int idx = t + 256 * ii;
    int kr = idx >> 6, ci = idx & 63;
    d1s[kr][ci] = d1[base + (k0 + kr) * 256 + i0 + ci];
  }
  __syncthreads();
  const int kl = t & 63, ig = t >> 6;
  float inv2 = z2s[kl];
  float accv = 0.f;
  for (int ii = 0; ii < 16; ++ii) {
    int il = ig * 16 + ii;
    int idx = base + (i0 + il) * 256 + k0 + kl;
    float a = Aout[idx];
    float e = __expf(fmaf(2.f * S_SCALE, a, -2.f * S_SCALE));
    float v = e * d2[idx] * d1s[kl][il] * z1s[il] * inv2;
    if (i0 + il != k0 + kl) accv += v;
  }
  accv = waveSum(accv);
  if ((t & 63) == 0) red[t >> 6] = accv;
  __syncthreads();
  if (t == 0) {
    float tot = red[0] + red[1] + red[2] + red[3];
    atomicAdd(loss, tot * (-1.f / 8192.f));
  }
}

extern "C" void kernel_launch(void* const* d_in, const int* in_sizes, int n_in,
                              void* d_out, int out_size, void* d_ws,
                              size_t ws_size, hipStream_t stream) {
  const float* x = (const float*)d_in[0];
  const float* conv_w = (const float*)d_in[1];
  const float* conv_b = (const float*)d_in[2];
  const float* fc1_w = (const float*)d_in[3];
  const float* fc1_b = (const float*)d_in[4];
  const float* drop1 = (const float*)d_in[5];
  const float* drop2 = (const float*)d_in[6];
  char* ws = (char*)d_ws;
  __bf16* W = (__bf16*)(ws + OFF_W);
  float* bias2 = (float*)(ws + OFF_BIAS);
  __bf16* fn = (__bf16*)(ws + OFF_FN);
  float* Zp = (float*)(ws + OFF_ZP);
  float* P123 = (float*)(ws + OFF_P);
  float* f = (float*)d_out;         // [8192,128]  (doubles as P0)
  float* Aout = f + 1048576;        // [32,256,256]
  float* loss = f + 3145728;        // scalar

  k_prep<<<224, 256, 0, stream>>>(conv_w, fc1_w, conv_b, fc1_b, W, bias2, loss);
  k_gemm1<<<dim3(128, 4), 256, 0, stream>>>(x, W, f, P123);
  k_fin<<<2048, 256, 0, stream>>>(f, P123, bias2, fn);
  k_gemm2<<<dim3(16, 32), 256, 0, stream>>>(fn, drop1, drop2, Aout, Zp);
  k_loss<<<dim3(16, 32), 256, 0, stream>>>(Aout, drop1, drop2, Zp, loss);
}